// Round 8
// baseline (227.164 us; speedup 1.0000x reference)
//
#include <hip/hip_runtime.h>

typedef _Float16 h16;
typedef __attribute__((ext_vector_type(8))) _Float16 half8;
typedef __attribute__((ext_vector_type(4))) _Float16 half4;
typedef __attribute__((ext_vector_type(4))) float f32x4;
typedef unsigned int u32;
typedef unsigned long long u64;

#define LOG2E 1.44269504088896340736f

__device__ __forceinline__ void gl_lds16(const void* g, void* l){
  __builtin_amdgcn_global_load_lds((const __attribute__((address_space(1))) u32*)g,
                                   (__attribute__((address_space(3))) u32*)l, 16, 0, 0);
}
__device__ __forceinline__ f32x4 mfma16(half8 a, half8 b, f32x4 c){
  return __builtin_amdgcn_mfma_f32_16x16x32_f16(a, b, c, 0, 0, 0);
}
__device__ __forceinline__ f32x4 fzero(){
  f32x4 z = {0.f, 0.f, 0.f, 0.f};
  return z;
}

// ---------------- K0: weights f32 -> f16 ----------------
__global__ void k_cvtw(const float* __restrict__ Wg, const float* __restrict__ Wf,
                       const float* __restrict__ Wh, const float* __restrict__ Wv,
                       h16* __restrict__ o){
  int i = blockIdx.x * 256 + threadIdx.x;     // 0..32767
  o[i]          = (h16)Wg[i];
  o[32768 + i]  = (h16)Wf[i];
  o[65536 + i]  = (h16)Wh[i];
  o[98304 + i]  = (h16)Wv[i];
}

// ---------------- K1: projections  Q,K:[b][p][128]  Vt:[b][128][p] ----------------
// round-5 proven version: 64-p tiles, grid 256.
__global__ __launch_bounds__(256, 2)
void k_proj(const float* __restrict__ x, const h16* __restrict__ Wgb,
            const h16* __restrict__ Whb, const h16* __restrict__ Wfb,
            h16* __restrict__ Q, h16* __restrict__ K, h16* __restrict__ Vt){
  __shared__ __align__(16) char Xl[64 * 512];   // [64 p][256 c] f16, XOR-swizzled
  int bid = blockIdx.x;
  int b = bid >> 6, p0 = (bid & 63) * 64;
  int tid = threadIdx.x;
  int w = tid >> 6, lane = tid & 63, g4 = lane >> 4, ln = lane & 15;

  #pragma unroll
  for (int pass = 0; pass < 4; ++pass){
    int idx = pass * 256 + tid;               // 0..1023
    int c4 = idx >> 4, p4 = idx & 15;
    const float* xp = x + ((size_t)b * 256 + c4 * 4) * 4096 + p0 + p4 * 4;
    float4 v0 = *(const float4*)(xp);
    float4 v1 = *(const float4*)(xp + 4096);
    float4 v2 = *(const float4*)(xp + 8192);
    float4 v3 = *(const float4*)(xp + 12288);
    #pragma unroll
    for (int i = 0; i < 4; ++i){
      int row = p4 * 4 + i;
      half4 v = { (h16)((&v0.x)[i]), (h16)((&v1.x)[i]),
                  (h16)((&v2.x)[i]), (h16)((&v3.x)[i]) };
      *(half4*)&Xl[row * 512 + ((c4 * 8) ^ ((row & 7) << 4))] = v;
    }
  }
  __syncthreads();

  half8 xf[4][8];
  #pragma unroll
  for (int pt = 0; pt < 4; ++pt){
    int p = pt * 16 + ln;
    #pragma unroll
    for (int ks = 0; ks < 8; ++ks)
      xf[pt][ks] = *(const half8*)&Xl[p * 512 + (((ks * 4 + g4) ^ (p & 7)) << 4)];
  }

  const h16* Ws0[3] = {Wgb, Whb, Wfb};
  #pragma unroll
  for (int mat = 0; mat < 3; ++mat){
    const h16* Wm = Ws0[mat];
    #pragma unroll
    for (int dtl = 0; dtl < 2; ++dtl){
      int drow = w * 32 + dtl * 16 + ln;
      half8 wf[8];
      #pragma unroll
      for (int ks = 0; ks < 8; ++ks)
        wf[ks] = *(const half8*)&Wm[(size_t)drow * 256 + ks * 32 + g4 * 8];
      #pragma unroll
      for (int pt = 0; pt < 4; ++pt){
        f32x4 acc = fzero();
        #pragma unroll
        for (int ks = 0; ks < 8; ++ks)
          acc = mfma16(wf[ks], xf[pt][ks], acc);
        int p = p0 + pt * 16 + ln;
        int dbase = w * 32 + dtl * 16 + g4 * 4;
        if (mat < 2){
          h16* Dst = (mat == 0) ? Q : K;
          half4 v = { (h16)acc[0], (h16)acc[1], (h16)acc[2], (h16)acc[3] };
          *(half4*)&Dst[((size_t)b * 4096 + p) * 128 + dbase] = v;
        } else {
          #pragma unroll
          for (int r = 0; r < 4; ++r)
            Vt[((size_t)b * 128 + dbase + r) * 4096 + p] = (h16)acc[r];
        }
      }
    }
  }
}

// ---------------- K2: flash attention — 16 q/wave, K-LDS dbuf, V direct-L2 ----------------
// grid 1024: b = bid>>8, qb = (bid>>2)&63 (64 q/block), sp = bid&3. 4 blocks/CU.
__global__ __launch_bounds__(256, 4)
void k_attn(const h16* __restrict__ Q, const h16* __restrict__ K,
            const h16* __restrict__ Vt, h16* __restrict__ Opart,
            float* __restrict__ Mb, float* __restrict__ Lb){
  __shared__ __align__(16) char Kl[2][16384];   // [64 key][128 d] f16 swz, dbuf
  __shared__ __align__(16) char Pl[4][2048];    // per-wave [16 q][64 k] f16 swz

  int bid = blockIdx.x;
  int b = bid >> 8, qb = (bid >> 2) & 63, sp = bid & 3;
  int tid = threadIdx.x;
  int w = tid >> 6, lane = tid & 63, g4 = lane >> 4, ln = lane & 15;
  int q0 = qb * 64 + w * 16;

  // Q fragments (B-operand of swapped QK^T): col=q=ln, k=d
  half8 qf[4];
  #pragma unroll
  for (int ks = 0; ks < 4; ++ks)
    qf[ks] = *(const half8*)&Q[((size_t)b * 4096 + q0 + ln) * 128 + ks * 32 + g4 * 8];

  f32x4 acc[8];
  #pragma unroll
  for (int dt = 0; dt < 8; ++dt) acc[dt] = fzero();
  float mrow = -1e30f, lrow = 0.f;

  int base0 = sp * 1024;
  const h16* vb = Vt + (size_t)b * 128 * 4096;

  auto stage = [&](int buf, int kv0){
    #pragma unroll
    for (int i = 0; i < 4; ++i){
      int off = i * 4096 + w * 1024 + lane * 16;
      int row = off >> 8, c16 = (off >> 4) & 15;
      gl_lds16(&K[((size_t)b * 4096 + kv0 + row) * 128 + ((c16 ^ (row & 7)) << 3)],
               &Kl[buf][i * 4096 + w * 1024]);
    }
  };

  stage(0, base0);
  __syncthreads();

  int cur = 0;
  for (int t = 0; t < 16; ++t){
    int kv0 = base0 + t * 64;
    if (t < 15) stage(cur ^ 1, kv0 + 64);       // prefetch next K tile

    // S^T = mfma(K, Q): lane holds S[key=kt*16+g4*4+r][q=ln]
    f32x4 s[4];
    #pragma unroll
    for (int kt = 0; kt < 4; ++kt) s[kt] = fzero();
    #pragma unroll
    for (int kt = 0; kt < 4; ++kt){
      int key = kt * 16 + ln;
      #pragma unroll
      for (int ks = 0; ks < 4; ++ks){
        half8 kf = *(const half8*)&Kl[cur][key * 256 + (((ks * 4 + g4) ^ (key & 7)) << 4)];
        s[kt] = mfma16(kf, qf[ks], s[kt]);
      }
    }

    // online softmax for row q=ln; defer-rescale THR=8
    float mx = -1e30f;
    #pragma unroll
    for (int kt = 0; kt < 4; ++kt)
      #pragma unroll
      for (int r = 0; r < 4; ++r) mx = fmaxf(mx, s[kt][r]);
    mx = fmaxf(mx, __shfl_xor(mx, 16));
    mx = fmaxf(mx, __shfl_xor(mx, 32));
    if (!__all(mx <= mrow + 8.f)){
      float mnew = fmaxf(mrow, mx);
      float scale = exp2f((mrow - mnew) * LOG2E);
      lrow *= scale;
      #pragma unroll
      for (int r = 0; r < 4; ++r){
        float sc = __shfl(scale, g4 * 4 + r);
        #pragma unroll
        for (int dt = 0; dt < 8; ++dt) acc[dt][r] *= sc;
      }
      mrow = mnew;
    }
    float ps = 0.f;
    #pragma unroll
    for (int kt = 0; kt < 4; ++kt){
      float e0 = exp2f((s[kt][0] - mrow) * LOG2E);
      float e1 = exp2f((s[kt][1] - mrow) * LOG2E);
      float e2 = exp2f((s[kt][2] - mrow) * LOG2E);
      float e3 = exp2f((s[kt][3] - mrow) * LOG2E);
      ps += (e0 + e1) + (e2 + e3);
      half4 pv = { (h16)e0, (h16)e1, (h16)e2, (h16)e3 };
      // P[q=ln][key=kt*16+g4*4+(0..3)]
      *(half4*)&Pl[w][ln * 128 + ((kt * 32 + g4 * 8) ^ ((ln & 7) << 4))] = pv;
    }
    ps += __shfl_xor(ps, 16);
    ps += __shfl_xor(ps, 32);
    lrow += ps;

    // PV: acc[dt] rows q=g4*4+r, cols d=dt*16+ln; V fragment direct from global
    #pragma unroll
    for (int st = 0; st < 2; ++st){
      half8 pa = *(const half8*)&Pl[w][ln * 128 + (((st * 4 + g4) ^ (ln & 7)) << 4)];
      #pragma unroll
      for (int dt = 0; dt < 8; ++dt){
        half8 vf = *(const half8*)&vb[((size_t)(dt * 16 + ln)) * 4096 + kv0 + st * 32 + g4 * 8];
        acc[dt] = mfma16(pa, vf, acc[dt]);
      }
    }

    __syncthreads();    // drains K prefetch; guards Kl[cur] overwrite next iter
    cur ^= 1;
  }

  // normalized partials (f16-safe under defer-max) + m,l
  float inv = 1.f / lrow;                       // per row q=ln
  int pb = (b * 64 + qb) * 4 + sp;
  #pragma unroll
  for (int r = 0; r < 4; ++r){
    float invr = __shfl(inv, g4 * 4 + r);
    int qloc = w * 16 + g4 * 4 + r;
    #pragma unroll
    for (int dt = 0; dt < 8; ++dt)
      Opart[(size_t)pb * 8192 + qloc * 128 + dt * 16 + ln] = (h16)(acc[dt][r] * invr);
  }
  if (lane < 16){
    Mb[pb * 64 + w * 16 + lane] = mrow;
    Lb[pb * 64 + w * 16 + lane] = lrow;
  }
}

// ---------------- K3: out = x + lambda * Wv @ combine(Opart)  (fused, no LDS) ----------------
__global__ __launch_bounds__(256, 2)
void k_oproj(const float* __restrict__ x, const h16* __restrict__ Wvb,
             const h16* __restrict__ Opart, const float* __restrict__ Mb,
             const float* __restrict__ Lb, const float* __restrict__ lamp,
             float* __restrict__ y){
  int bid = blockIdx.x;
  int b = bid >> 6, g64 = bid & 63;             // 64-q granule == 64-p tile
  int p0 = g64 * 64;
  int tid = threadIdx.x;
  int w = tid >> 6, lane = tid & 63, g4 = lane >> 4, ln = lane & 15;
  float lam = lamp[0];
  int base = (b * 64 + g64) * 4;

  // combine weights + O fragments, per p-row (lane ln)
  half8 of[4][4];
  #pragma unroll
  for (int pt = 0; pt < 4; ++pt){
    int p = pt * 16 + ln;
    float m0 = Mb[(base + 0) * 64 + p], m1 = Mb[(base + 1) * 64 + p];
    float m2 = Mb[(base + 2) * 64 + p], m3 = Mb[(base + 3) * 64 + p];
    float mmax = fmaxf(fmaxf(m0, m1), fmaxf(m2, m3));
    float w0 = exp2f((m0 - mmax) * LOG2E) * Lb[(base + 0) * 64 + p];
    float w1 = exp2f((m1 - mmax) * LOG2E) * Lb[(base + 1) * 64 + p];
    float w2 = exp2f((m2 - mmax) * LOG2E) * Lb[(base + 2) * 64 + p];
    float w3 = exp2f((m3 - mmax) * LOG2E) * Lb[(base + 3) * 64 + p];
    float inv = 1.f / (w0 + w1 + w2 + w3);
    w0 *= inv; w1 *= inv; w2 *= inv; w3 *= inv;
    #pragma unroll
    for (int ks = 0; ks < 4; ++ks){
      size_t eo = (size_t)p * 128 + ks * 32 + g4 * 8;
      half8 a0 = *(const half8*)&Opart[(size_t)(base + 0) * 8192 + eo];
      half8 a1 = *(const half8*)&Opart[(size_t)(base + 1) * 8192 + eo];
      half8 a2 = *(const half8*)&Opart[(size_t)(base + 2) * 8192 + eo];
      half8 a3 = *(const half8*)&Opart[(size_t)(base + 3) * 8192 + eo];
      half8 o;
      #pragma unroll
      for (int j = 0; j < 8; ++j)
        o[j] = (h16)(w0 * (float)a0[j] + w1 * (float)a1[j]
                   + w2 * (float)a2[j] + w3 * (float)a3[j]);
      of[pt][ks] = o;
    }
  }

  #pragma unroll
  for (int ctl = 0; ctl < 4; ++ctl){
    int crow = w * 64 + ctl * 16 + ln;
    half8 wf[4];
    #pragma unroll
    for (int ks = 0; ks < 4; ++ks)
      wf[ks] = *(const half8*)&Wvb[(size_t)crow * 128 + ks * 32 + g4 * 8];
    #pragma unroll
    for (int pt = 0; pt < 4; ++pt){
      f32x4 a = fzero();
      #pragma unroll
      for (int ks = 0; ks < 4; ++ks) a = mfma16(wf[ks], of[pt][ks], a);
      int p = p0 + pt * 16 + ln;
      int c = w * 64 + ctl * 16 + g4 * 4;
      #pragma unroll
      for (int r = 0; r < 4; ++r){
        size_t idx = ((size_t)b * 256 + c + r) * 4096 + p;
        y[idx] = x[idx] + lam * a[r];
      }
    }
  }
}

extern "C" void kernel_launch(void* const* d_in, const int* in_sizes, int n_in,
                              void* d_out, int out_size, void* d_ws, size_t ws_size,
                              hipStream_t stream) {
  const float* x   = (const float*)d_in[0];
  const float* Wg  = (const float*)d_in[1];
  const float* Wf  = (const float*)d_in[2];
  const float* Wh  = (const float*)d_in[3];
  const float* Wv  = (const float*)d_in[4];
  const float* lam = (const float*)d_in[5];

  h16* Wall  = (h16*)d_ws;                 // 131072 h16 (Wg,Wf,Wh,Wv f16)
  h16* Qb    = Wall + 131072;              // [4][4096][128]
  h16* Kb    = Qb + 2097152;               // [4][4096][128]
  h16* Vtb   = Kb + 2097152;               // [4][128][4096]
  h16* Opart = Vtb + 2097152;              // [1024][64][128] (normalized)
  float* Mb  = (float*)(Opart + 8388608);  // [1024][64]
  float* Lb  = Mb + 65536;                 // [1024][64]

  k_cvtw<<<128, 256, 0, stream>>>(Wg, Wf, Wh, Wv, Wall);
  k_proj<<<256, 256, 0, stream>>>(x, Wall /*Wg*/, Wall + 65536 /*Wh*/, Wall + 32768 /*Wf*/,
                                  Qb, Kb, Vtb);
  k_attn<<<1024, 256, 0, stream>>>(Qb, Kb, Vtb, Opart, Mb, Lb);
  k_oproj<<<256, 256, 0, stream>>>(x, Wall + 98304 /*Wv*/, Opart, Mb, Lb, lam, (float*)d_out);
}

// Round 9
// 177.072 us; speedup vs baseline: 1.2829x; 1.2829x over previous
//
#include <hip/hip_runtime.h>

typedef _Float16 h16;
typedef __attribute__((ext_vector_type(8))) _Float16 half8;
typedef __attribute__((ext_vector_type(4))) _Float16 half4;
typedef __attribute__((ext_vector_type(4))) float f32x4;
typedef unsigned int u32;
typedef unsigned long long u64;

#define LOG2E 1.44269504088896340736f

__device__ __forceinline__ void gl_lds16(const void* g, void* l){
  __builtin_amdgcn_global_load_lds((const __attribute__((address_space(1))) u32*)g,
                                   (__attribute__((address_space(3))) u32*)l, 16, 0, 0);
}
__device__ __forceinline__ f32x4 mfma16(half8 a, half8 b, f32x4 c){
  return __builtin_amdgcn_mfma_f32_16x16x32_f16(a, b, c, 0, 0, 0);
}
__device__ __forceinline__ f32x4 fzero(){
  f32x4 z = {0.f, 0.f, 0.f, 0.f};
  return z;
}
__device__ __forceinline__ half8 cvt8(const float* p){
  half8 r = { (h16)p[0], (h16)p[1], (h16)p[2], (h16)p[3],
              (h16)p[4], (h16)p[5], (h16)p[6], (h16)p[7] };
  return r;
}

// ---------------- K1: projections  Q,K:[b][p][128]  Vt:[b][128][p] ----------------
// 64-p tiles, grid 256. W read directly as f32 (no cvt kernel).
__global__ __launch_bounds__(256, 2)
void k_proj(const float* __restrict__ x, const float* __restrict__ Wg32,
            const float* __restrict__ Wh32, const float* __restrict__ Wf32,
            h16* __restrict__ Q, h16* __restrict__ K, h16* __restrict__ Vt){
  __shared__ __align__(16) char Xl[64 * 512];   // [64 p][256 c] f16, XOR-swizzled
  int bid = blockIdx.x;
  int b = bid >> 6, p0 = (bid & 63) * 64;
  int tid = threadIdx.x;
  int w = tid >> 6, lane = tid & 63, g4 = lane >> 4, ln = lane & 15;

  #pragma unroll
  for (int pass = 0; pass < 4; ++pass){
    int idx = pass * 256 + tid;               // 0..1023
    int c4 = idx >> 4, p4 = idx & 15;
    const float* xp = x + ((size_t)b * 256 + c4 * 4) * 4096 + p0 + p4 * 4;
    float4 v0 = *(const float4*)(xp);
    float4 v1 = *(const float4*)(xp + 4096);
    float4 v2 = *(const float4*)(xp + 8192);
    float4 v3 = *(const float4*)(xp + 12288);
    #pragma unroll
    for (int i = 0; i < 4; ++i){
      int row = p4 * 4 + i;
      half4 v = { (h16)((&v0.x)[i]), (h16)((&v1.x)[i]),
                  (h16)((&v2.x)[i]), (h16)((&v3.x)[i]) };
      *(half4*)&Xl[row * 512 + ((c4 * 8) ^ ((row & 7) << 4))] = v;
    }
  }
  __syncthreads();

  half8 xf[4][8];
  #pragma unroll
  for (int pt = 0; pt < 4; ++pt){
    int p = pt * 16 + ln;
    #pragma unroll
    for (int ks = 0; ks < 8; ++ks)
      xf[pt][ks] = *(const half8*)&Xl[p * 512 + (((ks * 4 + g4) ^ (p & 7)) << 4)];
  }

  const float* Ws0[3] = {Wg32, Wh32, Wf32};
  #pragma unroll
  for (int mat = 0; mat < 3; ++mat){
    const float* Wm = Ws0[mat];
    #pragma unroll
    for (int dtl = 0; dtl < 2; ++dtl){
      int drow = w * 32 + dtl * 16 + ln;
      half8 wf[8];
      #pragma unroll
      for (int ks = 0; ks < 8; ++ks)
        wf[ks] = cvt8(&Wm[(size_t)drow * 256 + ks * 32 + g4 * 8]);
      #pragma unroll
      for (int pt = 0; pt < 4; ++pt){
        f32x4 acc = fzero();
        #pragma unroll
        for (int ks = 0; ks < 8; ++ks)
          acc = mfma16(wf[ks], xf[pt][ks], acc);
        int p = p0 + pt * 16 + ln;
        int dbase = w * 32 + dtl * 16 + g4 * 4;
        if (mat < 2){
          h16* Dst = (mat == 0) ? Q : K;
          half4 v = { (h16)acc[0], (h16)acc[1], (h16)acc[2], (h16)acc[3] };
          *(half4*)&Dst[((size_t)b * 4096 + p) * 128 + dbase] = v;
        } else {
          #pragma unroll
          for (int r = 0; r < 4; ++r)
            Vt[((size_t)b * 128 + dbase + r) * 4096 + p] = (h16)acc[r];
        }
      }
    }
  }
}

// ---------------- K2: flash attention — 4 waves x 32 q, STATIC double-buffer ----------------
// grid 512: b = bid>>7, qb = (bid>>2)&31 (128 q/block), sp = bid&3. 2 blocks/CU.
__global__ __launch_bounds__(256, 2)
void k_attn(const h16* __restrict__ Q, const h16* __restrict__ K,
            const h16* __restrict__ Vt, h16* __restrict__ Opart,
            float* __restrict__ Mb, float* __restrict__ Lb){
  __shared__ __align__(16) char Kl[2][16384];   // [64 key][128 d] f16 swz, static dbuf
  __shared__ __align__(16) char Vl[2][16384];   // [128 d][64 key] f16 swz, static dbuf
  __shared__ __align__(16) char Pl[4][4096];    // per-wave [32 q][64 k] f16 swz

  int bid = blockIdx.x;
  int b = bid >> 7, qb = (bid >> 2) & 31, sp = bid & 3;
  int tid = threadIdx.x;
  int w = tid >> 6, lane = tid & 63, g4 = lane >> 4, ln = lane & 15;
  int q0 = qb * 128 + w * 32;

  half8 qf[2][4];
  #pragma unroll
  for (int qt = 0; qt < 2; ++qt)
    #pragma unroll
    for (int ks = 0; ks < 4; ++ks)
      qf[qt][ks] = *(const half8*)&Q[((size_t)b * 4096 + q0 + qt * 16 + ln) * 128 + ks * 32 + g4 * 8];

  f32x4 acc[2][8];
  #pragma unroll
  for (int qt = 0; qt < 2; ++qt)
    #pragma unroll
    for (int dt = 0; dt < 8; ++dt)
      acc[qt][dt] = fzero();
  float mrow[2] = {-1e30f, -1e30f};
  float lrow[2] = {0.f, 0.f};

  int base0 = sp * 1024;

  // stage into explicit (statically-indexed) LDS destinations
  auto stage = [&](char* kd, char* vd, int kv0){
    #pragma unroll
    for (int i = 0; i < 4; ++i){
      int off = i * 4096 + w * 1024 + lane * 16;
      int row = off >> 8, c16 = (off >> 4) & 15;
      gl_lds16(&K[((size_t)b * 4096 + kv0 + row) * 128 + ((c16 ^ (row & 7)) << 3)],
               kd + i * 4096 + w * 1024);
    }
    #pragma unroll
    for (int i = 0; i < 4; ++i){
      int off = i * 4096 + w * 1024 + lane * 16;
      int row = off >> 7, c16 = (off >> 4) & 7;
      gl_lds16(&Vt[((size_t)b * 128 + row) * 4096 + kv0 + ((c16 ^ (row & 7)) << 3)],
               vd + i * 4096 + w * 1024);
    }
  };

  stage(&Kl[0][0], &Vl[0][0], base0);
  __syncthreads();

  for (int t2 = 0; t2 < 8; ++t2){
    #pragma unroll
    for (int h = 0; h < 2; ++h){              // h is compile-time after unroll
      int t = t2 * 2 + h;
      int kv0 = base0 + t * 64;
      if ((h == 0) | (t2 < 7))
        stage(&Kl[1 - h][0], &Vl[1 - h][0], kv0 + 64);   // prefetch, disjoint buffer

      // S^T = mfma(K, Q)
      f32x4 s[4][2];
      #pragma unroll
      for (int kt = 0; kt < 4; ++kt)
        #pragma unroll
        for (int qt = 0; qt < 2; ++qt) s[kt][qt] = fzero();
      #pragma unroll
      for (int kt = 0; kt < 4; ++kt){
        int key = kt * 16 + ln;
        #pragma unroll
        for (int ks = 0; ks < 4; ++ks){
          half8 kf = *(const half8*)&Kl[h][key * 256 + (((ks * 4 + g4) ^ (key & 7)) << 4)];
          #pragma unroll
          for (int qt = 0; qt < 2; ++qt)
            s[kt][qt] = mfma16(kf, qf[qt][ks], s[kt][qt]);
        }
      }

      // online softmax with defer-rescale (THR=8)
      #pragma unroll
      for (int qt = 0; qt < 2; ++qt){
        float mx = -1e30f;
        #pragma unroll
        for (int kt = 0; kt < 4; ++kt)
          #pragma unroll
          for (int r = 0; r < 4; ++r) mx = fmaxf(mx, s[kt][qt][r]);
        mx = fmaxf(mx, __shfl_xor(mx, 16));
        mx = fmaxf(mx, __shfl_xor(mx, 32));
        if (!__all(mx <= mrow[qt] + 8.f)){
          float mnew = fmaxf(mrow[qt], mx);
          float scale = exp2f((mrow[qt] - mnew) * LOG2E);
          lrow[qt] *= scale;
          #pragma unroll
          for (int r = 0; r < 4; ++r){
            float sc = __shfl(scale, g4 * 4 + r);
            #pragma unroll
            for (int dt = 0; dt < 8; ++dt) acc[qt][dt][r] *= sc;
          }
          mrow[qt] = mnew;
        }
        float ps = 0.f;
        int q = qt * 16 + ln;
        #pragma unroll
        for (int kt = 0; kt < 4; ++kt){
          float e0 = exp2f((s[kt][qt][0] - mrow[qt]) * LOG2E);
          float e1 = exp2f((s[kt][qt][1] - mrow[qt]) * LOG2E);
          float e2 = exp2f((s[kt][qt][2] - mrow[qt]) * LOG2E);
          float e3 = exp2f((s[kt][qt][3] - mrow[qt]) * LOG2E);
          ps += (e0 + e1) + (e2 + e3);
          half4 pv = { (h16)e0, (h16)e1, (h16)e2, (h16)e3 };
          *(half4*)&Pl[w][q * 128 + ((kt * 32 + g4 * 8) ^ ((q & 7) << 4))] = pv;
        }
        ps += __shfl_xor(ps, 16);
        ps += __shfl_xor(ps, 32);
        lrow[qt] += ps;
      }

      // PV
      #pragma unroll
      for (int st = 0; st < 2; ++st){
        half8 pa[2];
        #pragma unroll
        for (int qt = 0; qt < 2; ++qt){
          int q = qt * 16 + ln;
          pa[qt] = *(const half8*)&Pl[w][q * 128 + (((st * 4 + g4) ^ (q & 7)) << 4)];
        }
        #pragma unroll
        for (int dt = 0; dt < 8; ++dt){
          int row = dt * 16 + ln;
          half8 vf = *(const half8*)&Vl[h][row * 128 + (((st * 4 + g4) ^ (row & 7)) << 4)];
          #pragma unroll
          for (int qt = 0; qt < 2; ++qt)
            acc[qt][dt] = mfma16(pa[qt], vf, acc[qt][dt]);
        }
      }

      __syncthreads();   // drains this iter's prefetch (vmcnt0) + guards buffer swap
    }
  }

  // normalized partials (f16-safe under defer-max) + m,l
  int pb = (b * 64 + qb * 2 + (w >> 1)) * 4 + sp;
  #pragma unroll
  for (int qt = 0; qt < 2; ++qt){
    float inv = 1.f / lrow[qt];
    #pragma unroll
    for (int r = 0; r < 4; ++r){
      float invr = __shfl(inv, g4 * 4 + r);
      int qloc = (w & 1) * 32 + qt * 16 + g4 * 4 + r;
      #pragma unroll
      for (int dt = 0; dt < 8; ++dt)
        Opart[(size_t)pb * 8192 + qloc * 128 + dt * 16 + ln] = (h16)(acc[qt][dt][r] * invr);
    }
  }
  if (lane < 16){
    #pragma unroll
    for (int qt = 0; qt < 2; ++qt){
      int qloc = (w & 1) * 32 + qt * 16 + lane;
      Mb[pb * 64 + qloc] = mrow[qt];
      Lb[pb * 64 + qloc] = lrow[qt];
    }
  }
}

// ---------------- K3: out = x + lambda * Wv @ combine(Opart)  (fused) ----------------
__global__ __launch_bounds__(256, 2)
void k_oproj(const float* __restrict__ x, const float* __restrict__ Wv32,
             const h16* __restrict__ Opart, const float* __restrict__ Mb,
             const float* __restrict__ Lb, const float* __restrict__ lamp,
             float* __restrict__ y){
  int bid = blockIdx.x;
  int b = bid >> 6, g64 = bid & 63;             // 64-q granule == 64-p tile
  int p0 = g64 * 64;
  int tid = threadIdx.x;
  int w = tid >> 6, lane = tid & 63, g4 = lane >> 4, ln = lane & 15;
  float lam = lamp[0];
  int base = (b * 64 + g64) * 4;

  half8 of[4][4];
  #pragma unroll
  for (int pt = 0; pt < 4; ++pt){
    int p = pt * 16 + ln;
    float m0 = Mb[(base + 0) * 64 + p], m1 = Mb[(base + 1) * 64 + p];
    float m2 = Mb[(base + 2) * 64 + p], m3 = Mb[(base + 3) * 64 + p];
    float mmax = fmaxf(fmaxf(m0, m1), fmaxf(m2, m3));
    float w0 = exp2f((m0 - mmax) * LOG2E) * Lb[(base + 0) * 64 + p];
    float w1 = exp2f((m1 - mmax) * LOG2E) * Lb[(base + 1) * 64 + p];
    float w2 = exp2f((m2 - mmax) * LOG2E) * Lb[(base + 2) * 64 + p];
    float w3 = exp2f((m3 - mmax) * LOG2E) * Lb[(base + 3) * 64 + p];
    float inv = 1.f / (w0 + w1 + w2 + w3);
    w0 *= inv; w1 *= inv; w2 *= inv; w3 *= inv;
    #pragma unroll
    for (int ks = 0; ks < 4; ++ks){
      size_t eo = (size_t)p * 128 + ks * 32 + g4 * 8;
      half8 a0 = *(const half8*)&Opart[(size_t)(base + 0) * 8192 + eo];
      half8 a1 = *(const half8*)&Opart[(size_t)(base + 1) * 8192 + eo];
      half8 a2 = *(const half8*)&Opart[(size_t)(base + 2) * 8192 + eo];
      half8 a3 = *(const half8*)&Opart[(size_t)(base + 3) * 8192 + eo];
      half8 o;
      #pragma unroll
      for (int j = 0; j < 8; ++j)
        o[j] = (h16)(w0 * (float)a0[j] + w1 * (float)a1[j]
                   + w2 * (float)a2[j] + w3 * (float)a3[j]);
      of[pt][ks] = o;
    }
  }

  #pragma unroll
  for (int ctl = 0; ctl < 4; ++ctl){
    int crow = w * 64 + ctl * 16 + ln;
    half8 wf[4];
    #pragma unroll
    for (int ks = 0; ks < 4; ++ks)
      wf[ks] = cvt8(&Wv32[(size_t)crow * 128 + ks * 32 + g4 * 8]);
    #pragma unroll
    for (int pt = 0; pt < 4; ++pt){
      f32x4 a = fzero();
      #pragma unroll
      for (int ks = 0; ks < 4; ++ks) a = mfma16(wf[ks], of[pt][ks], a);
      int p = p0 + pt * 16 + ln;
      int c = w * 64 + ctl * 16 + g4 * 4;
      #pragma unroll
      for (int r = 0; r < 4; ++r){
        size_t idx = ((size_t)b * 256 + c + r) * 4096 + p;
        y[idx] = x[idx] + lam * a[r];
      }
    }
  }
}

extern "C" void kernel_launch(void* const* d_in, const int* in_sizes, int n_in,
                              void* d_out, int out_size, void* d_ws, size_t ws_size,
                              hipStream_t stream) {
  const float* x   = (const float*)d_in[0];
  const float* Wg  = (const float*)d_in[1];
  const float* Wf  = (const float*)d_in[2];
  const float* Wh  = (const float*)d_in[3];
  const float* Wv  = (const float*)d_in[4];
  const float* lam = (const float*)d_in[5];

  h16* Qb    = (h16*)d_ws;                 // [4][4096][128]
  h16* Kb    = Qb + 2097152;               // [4][4096][128]
  h16* Vtb   = Kb + 2097152;               // [4][128][4096]
  h16* Opart = Vtb + 2097152;              // [1024][64][128] (normalized)
  float* Mb  = (float*)(Opart + 8388608);  // [1024][64]
  float* Lb  = Mb + 65536;                 // [1024][64]

  k_proj<<<256, 256, 0, stream>>>(x, Wg, Wh, Wf, Qb, Kb, Vtb);
  k_attn<<<512, 256, 0, stream>>>(Qb, Kb, Vtb, Opart, Mb, Lb);
  k_oproj<<<256, 256, 0, stream>>>(x, Wv, Opart, Mb, Lb, lam, (float*)d_out);
}

// Round 13
// 158.897 us; speedup vs baseline: 1.4296x; 1.1144x over previous
//
#include <hip/hip_runtime.h>

typedef _Float16 h16;
typedef __attribute__((ext_vector_type(8))) _Float16 half8;
typedef __attribute__((ext_vector_type(4))) _Float16 half4;
typedef __attribute__((ext_vector_type(4))) float f32x4;
typedef unsigned int u32;
typedef unsigned long long u64;

#define LOG2E 1.44269504088896340736f

__device__ __forceinline__ void gl_lds16(const void* g, void* l){
  __builtin_amdgcn_global_load_lds((const __attribute__((address_space(1))) u32*)g,
                                   (__attribute__((address_space(3))) u32*)l, 16, 0, 0);
}
__device__ __forceinline__ f32x4 mfma16(half8 a, half8 b, f32x4 c){
  return __builtin_amdgcn_mfma_f32_16x16x32_f16(a, b, c, 0, 0, 0);
}
__device__ __forceinline__ f32x4 fzero(){
  f32x4 z = {0.f, 0.f, 0.f, 0.f};
  return z;
}
__device__ __forceinline__ u32 pkrtz(float a, float b){
  return __builtin_bit_cast(u32, __builtin_amdgcn_cvt_pkrtz(a, b));
}

// ---------------- K0: weights f32 -> f16 ----------------
__global__ void k_cvtw(const float* __restrict__ Wg, const float* __restrict__ Wf,
                       const float* __restrict__ Wh, const float* __restrict__ Wv,
                       h16* __restrict__ o){
  int i = blockIdx.x * 256 + threadIdx.x;     // 0..32767
  o[i]          = (h16)Wg[i];
  o[32768 + i]  = (h16)Wf[i];
  o[65536 + i]  = (h16)Wh[i];
  o[98304 + i]  = (h16)Wv[i];
}

// ---------------- K1: projections  Q,K:[b][p][128]  Vt:[b][128][p] ----------------
// 64-p tiles, grid 256, h16 weights. Q pre-scaled by log2(e).
__global__ __launch_bounds__(256, 2)
void k_proj(const float* __restrict__ x, const h16* __restrict__ Wgb,
            const h16* __restrict__ Whb, const h16* __restrict__ Wfb,
            h16* __restrict__ Q, h16* __restrict__ K, h16* __restrict__ Vt){
  __shared__ __align__(16) char Xl[64 * 512];   // [64 p][256 c] f16, XOR-swizzled
  int bid = blockIdx.x;
  int b = bid >> 6, p0 = (bid & 63) * 64;
  int tid = threadIdx.x;
  int w = tid >> 6, lane = tid & 63, g4 = lane >> 4, ln = lane & 15;

  #pragma unroll
  for (int pass = 0; pass < 4; ++pass){
    int idx = pass * 256 + tid;               // 0..1023
    int c4 = idx >> 4, p4 = idx & 15;
    const float* xp = x + ((size_t)b * 256 + c4 * 4) * 4096 + p0 + p4 * 4;
    float4 v0 = *(const float4*)(xp);
    float4 v1 = *(const float4*)(xp + 4096);
    float4 v2 = *(const float4*)(xp + 8192);
    float4 v3 = *(const float4*)(xp + 12288);
    #pragma unroll
    for (int i = 0; i < 4; ++i){
      int row = p4 * 4 + i;
      half4 v = { (h16)((&v0.x)[i]), (h16)((&v1.x)[i]),
                  (h16)((&v2.x)[i]), (h16)((&v3.x)[i]) };
      *(half4*)&Xl[row * 512 + ((c4 * 8) ^ ((row & 7) << 4))] = v;
    }
  }
  __syncthreads();

  half8 xf[4][8];
  #pragma unroll
  for (int pt = 0; pt < 4; ++pt){
    int p = pt * 16 + ln;
    #pragma unroll
    for (int ks = 0; ks < 8; ++ks)
      xf[pt][ks] = *(const half8*)&Xl[p * 512 + (((ks * 4 + g4) ^ (p & 7)) << 4)];
  }

  const h16* Ws0[3] = {Wgb, Whb, Wfb};
  #pragma unroll
  for (int mat = 0; mat < 3; ++mat){
    const h16* Wm = Ws0[mat];
    float osc = (mat == 0) ? LOG2E : 1.0f;    // fold log2e into Q
    #pragma unroll
    for (int dtl = 0; dtl < 2; ++dtl){
      int drow = w * 32 + dtl * 16 + ln;
      half8 wf[8];
      #pragma unroll
      for (int ks = 0; ks < 8; ++ks)
        wf[ks] = *(const half8*)&Wm[(size_t)drow * 256 + ks * 32 + g4 * 8];
      #pragma unroll
      for (int pt = 0; pt < 4; ++pt){
        f32x4 acc = fzero();
        #pragma unroll
        for (int ks = 0; ks < 8; ++ks)
          acc = mfma16(wf[ks], xf[pt][ks], acc);
        int p = p0 + pt * 16 + ln;
        int dbase = w * 32 + dtl * 16 + g4 * 4;
        if (mat < 2){
          h16* Dst = (mat == 0) ? Q : K;
          half4 v = { (h16)(acc[0] * osc), (h16)(acc[1] * osc),
                      (h16)(acc[2] * osc), (h16)(acc[3] * osc) };
          *(half4*)&Dst[((size_t)b * 4096 + p) * 128 + dbase] = v;
        } else {
          #pragma unroll
          for (int r = 0; r < 4; ++r)
            Vt[((size_t)b * 128 + dbase + r) * 4096 + p] = (h16)acc[r];
        }
      }
    }
  }
}

// ---------------- K2: flash attention — 16 q/wave, KVBLK=32, 4 blocks/CU ----------------
// grid 1024: b = bid>>8, qb = (bid>>2)&63 (64 q/block), sp = bid&3.
__global__ __launch_bounds__(256, 4)
void k_attn(const h16* __restrict__ Q, const h16* __restrict__ K,
            const h16* __restrict__ Vt, h16* __restrict__ Opart,
            float* __restrict__ Mb, float* __restrict__ Lb){
  __shared__ __align__(16) char Kl[2][8192];    // [32 key][128 d] f16 swz, static dbuf
  __shared__ __align__(16) char Vl[2][8192];    // [128 d][32 key] f16 swz, static dbuf
  __shared__ __align__(16) char Pl[4][1280];    // per-wave [16 q][32 k] f16, 80B pitch

  int bid = blockIdx.x;
  int b = bid >> 8, qb = (bid >> 2) & 63, sp = bid & 3;
  int tid = threadIdx.x;
  int w = tid >> 6, lane = tid & 63, g4 = lane >> 4, ln = lane & 15;
  int q0 = qb * 64 + w * 16;

  // Q fragments (B-operand of swapped QK^T): col=q=ln, k=d
  half8 qf[4];
  #pragma unroll
  for (int ks = 0; ks < 4; ++ks)
    qf[ks] = *(const half8*)&Q[((size_t)b * 4096 + q0 + ln) * 128 + ks * 32 + g4 * 8];

  f32x4 acc[8];
  #pragma unroll
  for (int dt = 0; dt < 8; ++dt) acc[dt] = fzero();
  float mrow = -1e30f, lrow = 0.f;              // log2-domain max

  int base0 = sp * 1024;

  auto stage = [&](char* kd, char* vd, int kv0){
    #pragma unroll
    for (int i = 0; i < 2; ++i){
      int off = i * 4096 + w * 1024 + lane * 16;
      int row = off >> 8, c16 = (off >> 4) & 15;
      gl_lds16(&K[((size_t)b * 4096 + kv0 + row) * 128 + ((c16 ^ (row & 7)) << 3)],
               kd + i * 4096 + w * 1024);
    }
    #pragma unroll
    for (int i = 0; i < 2; ++i){
      int off = i * 4096 + w * 1024 + lane * 16;
      int row = off >> 6, c4 = (off >> 4) & 3;
      gl_lds16(&Vt[((size_t)b * 128 + row) * 4096 + kv0 + ((c4 ^ ((row >> 1) & 3)) << 3)],
               vd + i * 4096 + w * 1024);
    }
  };

  stage(&Kl[0][0], &Vl[0][0], base0);
  __syncthreads();

  for (int t2 = 0; t2 < 16; ++t2){
    #pragma unroll
    for (int h = 0; h < 2; ++h){              // compile-time buffer index
      int t = t2 * 2 + h;
      int kv0 = base0 + t * 32;
      if ((h == 0) | (t2 < 15))
        stage(&Kl[1 - h][0], &Vl[1 - h][0], kv0 + 32);   // prefetch into other buffer

      // S^T = mfma(K, Q): lane holds S[key=kt*16+g4*4+r][q=ln] (log2-scaled)
      f32x4 s[2];
      #pragma unroll
      for (int kt = 0; kt < 2; ++kt) s[kt] = fzero();
      #pragma unroll
      for (int kt = 0; kt < 2; ++kt){
        int key = kt * 16 + ln;
        #pragma unroll
        for (int ks = 0; ks < 4; ++ks){
          half8 kf = *(const half8*)&Kl[h][key * 256 + (((ks * 4 + g4) ^ (key & 7)) << 4)];
          s[kt] = mfma16(kf, qf[ks], s[kt]);
        }
      }

      // online softmax (row q=ln), defer-rescale THR=11.5 (log2 domain)
      float mx = fmaxf(fmaxf(fmaxf(s[0][0], s[0][1]), fmaxf(s[0][2], s[0][3])),
                       fmaxf(fmaxf(s[1][0], s[1][1]), fmaxf(s[1][2], s[1][3])));
      mx = fmaxf(mx, __shfl_xor(mx, 16));
      mx = fmaxf(mx, __shfl_xor(mx, 32));
      if (!__all(mx <= mrow + 11.5f)){
        float mnew = fmaxf(mrow, mx);
        float scale = exp2f(mrow - mnew);
        lrow *= scale;
        #pragma unroll
        for (int r = 0; r < 4; ++r){
          float sc = __shfl(scale, g4 * 4 + r);
          #pragma unroll
          for (int dt = 0; dt < 8; ++dt) acc[dt][r] *= sc;
        }
        mrow = mnew;
      }
      float ps = 0.f;
      #pragma unroll
      for (int kt = 0; kt < 2; ++kt){
        float e0 = exp2f(s[kt][0] - mrow);
        float e1 = exp2f(s[kt][1] - mrow);
        float e2 = exp2f(s[kt][2] - mrow);
        float e3 = exp2f(s[kt][3] - mrow);
        ps += (e0 + e1) + (e2 + e3);
        u64 v = (u64)pkrtz(e0, e1) | ((u64)pkrtz(e2, e3) << 32);
        // P[q=ln][key=kt*16+g4*4+(0..3)], 80B pitch (bank-safe, no swizzle)
        *(u64*)&Pl[w][ln * 80 + kt * 32 + g4 * 8] = v;
      }
      ps += __shfl_xor(ps, 16);
      ps += __shfl_xor(ps, 32);
      lrow += ps;

      // PV: single K=32 MFMA chain; pa = P[q=ln][k=g4*8+j]
      half8 pa = *(const half8*)&Pl[w][ln * 80 + g4 * 16];
      #pragma unroll
      for (int dt = 0; dt < 8; ++dt){
        int row = dt * 16 + ln;
        half8 vf = *(const half8*)&Vl[h][row * 64 + ((g4 ^ ((row >> 1) & 3)) << 4)];
        acc[dt] = mfma16(pa, vf, acc[dt]);
      }

      __syncthreads();   // drains prefetch (vmcnt0) + guards buffer swap
    }
  }

  // normalized partials (f16-safe) + m,l  (m in log2 domain)
  float inv = 1.f / lrow;
  int pb = (b * 64 + qb) * 4 + sp;
  #pragma unroll
  for (int r = 0; r < 4; ++r){
    float invr = __shfl(inv, g4 * 4 + r);
    int qloc = w * 16 + g4 * 4 + r;
    #pragma unroll
    for (int dt = 0; dt < 8; ++dt)
      Opart[(size_t)pb * 8192 + qloc * 128 + dt * 16 + ln] = (h16)(acc[dt][r] * invr);
  }
  if (lane < 16){
    Mb[pb * 64 + w * 16 + lane] = mrow;
    Lb[pb * 64 + w * 16 + lane] = lrow;
  }
}

// ---------------- K3: out = x + lambda * Wv @ combine(Opart)  (fused, h16 Wv) ----------------
__global__ __launch_bounds__(256, 2)
void k_oproj(const float* __restrict__ x, const h16* __restrict__ Wvb,
             const h16* __restrict__ Opart, const float* __restrict__ Mb,
             const float* __restrict__ Lb, const float* __restrict__ lamp,
             float* __restrict__ y){
  int bid = blockIdx.x;
  int b = bid >> 6, g64 = bid & 63;             // 64-q granule == 64-p tile
  int p0 = g64 * 64;
  int tid = threadIdx.x;
  int w = tid >> 6, lane = tid & 63, g4 = lane >> 4, ln = lane & 15;
  float lam = lamp[0];
  int base = (b * 64 + g64) * 4;

  half8 of[4][4];
  #pragma unroll
  for (int pt = 0; pt < 4; ++pt){
    int p = pt * 16 + ln;
    float m0 = Mb[(base + 0) * 64 + p], m1 = Mb[(base + 1) * 64 + p];
    float m2 = Mb[(base + 2) * 64 + p], m3 = Mb[(base + 3) * 64 + p];
    float mmax = fmaxf(fmaxf(m0, m1), fmaxf(m2, m3));
    float w0 = exp2f(m0 - mmax) * Lb[(base + 0) * 64 + p];   // m already log2-domain
    float w1 = exp2f(m1 - mmax) * Lb[(base + 1) * 64 + p];
    float w2 = exp2f(m2 - mmax) * Lb[(base + 2) * 64 + p];
    float w3 = exp2f(m3 - mmax) * Lb[(base + 3) * 64 + p];
    float inv = 1.f / (w0 + w1 + w2 + w3);
    w0 *= inv; w1 *= inv; w2 *= inv; w3 *= inv;
    #pragma unroll
    for (int ks = 0; ks < 4; ++ks){
      size_t eo = (size_t)p * 128 + ks * 32 + g4 * 8;
      half8 a0 = *(const half8*)&Opart[(size_t)(base + 0) * 8192 + eo];
      half8 a1 = *(const half8*)&Opart[(size_t)(base + 1) * 8192 + eo];
      half8 a2 = *(const half8*)&Opart[(size_t)(base + 2) * 8192 + eo];
      half8 a3 = *(const half8*)&Opart[(size_t)(base + 3) * 8192 + eo];
      half8 o;
      #pragma unroll
      for (int j = 0; j < 8; ++j)
        o[j] = (h16)(w0 * (float)a0[j] + w1 * (float)a1[j]
                   + w2 * (float)a2[j] + w3 * (float)a3[j]);
      of[pt][ks] = o;
    }
  }

  #pragma unroll
  for (int ctl = 0; ctl < 4; ++ctl){
    int crow = w * 64 + ctl * 16 + ln;
    half8 wf[4];
    #pragma unroll
    for (int ks = 0; ks < 4; ++ks)
      wf[ks] = *(const half8*)&Wvb[(size_t)crow * 128 + ks * 32 + g4 * 8];
    #pragma unroll
    for (int pt = 0; pt < 4; ++pt){
      f32x4 a = fzero();
      #pragma unroll
      for (int ks = 0; ks < 4; ++ks) a = mfma16(wf[ks], of[pt][ks], a);
      int p = p0 + pt * 16 + ln;
      int c = w * 64 + ctl * 16 + g4 * 4;
      #pragma unroll
      for (int r = 0; r < 4; ++r){
        size_t idx = ((size_t)b * 256 + c + r) * 4096 + p;
        y[idx] = x[idx] + lam * a[r];
      }
    }
  }
}

extern "C" void kernel_launch(void* const* d_in, const int* in_sizes, int n_in,
                              void* d_out, int out_size, void* d_ws, size_t ws_size,
                              hipStream_t stream) {
  const float* x   = (const float*)d_in[0];
  const float* Wg  = (const float*)d_in[1];
  const float* Wf  = (const float*)d_in[2];
  const float* Wh  = (const float*)d_in[3];
  const float* Wv  = (const float*)d_in[4];
  const float* lam = (const float*)d_in[5];

  h16* Wall  = (h16*)d_ws;                 // 131072 h16 (Wg,Wf,Wh,Wv f16)
  h16* Qb    = Wall + 131072;              // [4][4096][128] (pre-scaled by log2e)
  h16* Kb    = Qb + 2097152;               // [4][4096][128]
  h16* Vtb   = Kb + 2097152;               // [4][128][4096]
  h16* Opart = Vtb + 2097152;              // [1024][64][128] (normalized)
  float* Mb  = (float*)(Opart + 8388608);  // [1024][64] (log2-domain)
  float* Lb  = Mb + 65536;                 // [1024][64]

  k_cvtw<<<128, 256, 0, stream>>>(Wg, Wf, Wh, Wv, Wall);
  k_proj<<<256, 256, 0, stream>>>(x, Wall /*Wg*/, Wall + 65536 /*Wh*/, Wall + 32768 /*Wf*/,
                                  Qb, Kb, Vtb);
  k_attn<<<1024, 256, 0, stream>>>(Qb, Kb, Vtb, Opart, Mb, Lb);
  k_oproj<<<256, 256, 0, stream>>>(x, Wall + 98304 /*Wv*/, Opart, Mb, Lb, lam, (float*)d_out);
}

// Round 14
// 151.975 us; speedup vs baseline: 1.4947x; 1.0455x over previous
//
#include <hip/hip_runtime.h>

typedef _Float16 h16;
typedef __attribute__((ext_vector_type(8))) _Float16 half8;
typedef __attribute__((ext_vector_type(4))) _Float16 half4;
typedef __attribute__((ext_vector_type(4))) float f32x4;
typedef unsigned int u32;
typedef unsigned long long u64;

#define LOG2E 1.44269504088896340736f

__device__ __forceinline__ void gl_lds16(const void* g, void* l){
  __builtin_amdgcn_global_load_lds((const __attribute__((address_space(1))) u32*)g,
                                   (__attribute__((address_space(3))) u32*)l, 16, 0, 0);
}
__device__ __forceinline__ f32x4 mfma16(half8 a, half8 b, f32x4 c){
  return __builtin_amdgcn_mfma_f32_16x16x32_f16(a, b, c, 0, 0, 0);
}
__device__ __forceinline__ f32x4 fzero(){
  f32x4 z = {0.f, 0.f, 0.f, 0.f};
  return z;
}
__device__ __forceinline__ u32 pkrtz(float a, float b){
  return __builtin_bit_cast(u32, __builtin_amdgcn_cvt_pkrtz(a, b));
}

// ---------------- K0: weights f32 -> f16 ----------------
__global__ void k_cvtw(const float* __restrict__ Wg, const float* __restrict__ Wf,
                       const float* __restrict__ Wh, const float* __restrict__ Wv,
                       h16* __restrict__ o){
  int i = blockIdx.x * 256 + threadIdx.x;     // 0..32767
  o[i]          = (h16)Wg[i];
  o[32768 + i]  = (h16)Wf[i];
  o[65536 + i]  = (h16)Wh[i];
  o[98304 + i]  = (h16)Wv[i];
}

// ---------------- K1: projections  Q,K:[b][p][128]  Vt:[b][128][p] ----------------
// 64-p tiles, grid 256, h16 weights. Q pre-scaled by log2(e).
__global__ __launch_bounds__(256, 2)
void k_proj(const float* __restrict__ x, const h16* __restrict__ Wgb,
            const h16* __restrict__ Whb, const h16* __restrict__ Wfb,
            h16* __restrict__ Q, h16* __restrict__ K, h16* __restrict__ Vt){
  __shared__ __align__(16) char Xl[64 * 512];   // [64 p][256 c] f16, XOR-swizzled
  int bid = blockIdx.x;
  int b = bid >> 6, p0 = (bid & 63) * 64;
  int tid = threadIdx.x;
  int w = tid >> 6, lane = tid & 63, g4 = lane >> 4, ln = lane & 15;

  #pragma unroll
  for (int pass = 0; pass < 4; ++pass){
    int idx = pass * 256 + tid;               // 0..1023
    int c4 = idx >> 4, p4 = idx & 15;
    const float* xp = x + ((size_t)b * 256 + c4 * 4) * 4096 + p0 + p4 * 4;
    float4 v0 = *(const float4*)(xp);
    float4 v1 = *(const float4*)(xp + 4096);
    float4 v2 = *(const float4*)(xp + 8192);
    float4 v3 = *(const float4*)(xp + 12288);
    #pragma unroll
    for (int i = 0; i < 4; ++i){
      int row = p4 * 4 + i;
      half4 v = { (h16)((&v0.x)[i]), (h16)((&v1.x)[i]),
                  (h16)((&v2.x)[i]), (h16)((&v3.x)[i]) };
      *(half4*)&Xl[row * 512 + ((c4 * 8) ^ ((row & 7) << 4))] = v;
    }
  }
  __syncthreads();

  half8 xf[4][8];
  #pragma unroll
  for (int pt = 0; pt < 4; ++pt){
    int p = pt * 16 + ln;
    #pragma unroll
    for (int ks = 0; ks < 8; ++ks)
      xf[pt][ks] = *(const half8*)&Xl[p * 512 + (((ks * 4 + g4) ^ (p & 7)) << 4)];
  }

  const h16* Ws0[3] = {Wgb, Whb, Wfb};
  #pragma unroll
  for (int mat = 0; mat < 3; ++mat){
    const h16* Wm = Ws0[mat];
    float osc = (mat == 0) ? LOG2E : 1.0f;    // fold log2e into Q
    #pragma unroll
    for (int dtl = 0; dtl < 2; ++dtl){
      int drow = w * 32 + dtl * 16 + ln;
      half8 wf[8];
      #pragma unroll
      for (int ks = 0; ks < 8; ++ks)
        wf[ks] = *(const half8*)&Wm[(size_t)drow * 256 + ks * 32 + g4 * 8];
      #pragma unroll
      for (int pt = 0; pt < 4; ++pt){
        f32x4 acc = fzero();
        #pragma unroll
        for (int ks = 0; ks < 8; ++ks)
          acc = mfma16(wf[ks], xf[pt][ks], acc);
        int p = p0 + pt * 16 + ln;
        int dbase = w * 32 + dtl * 16 + g4 * 4;
        if (mat < 2){
          h16* Dst = (mat == 0) ? Q : K;
          half4 v = { (h16)(acc[0] * osc), (h16)(acc[1] * osc),
                      (h16)(acc[2] * osc), (h16)(acc[3] * osc) };
          *(half4*)&Dst[((size_t)b * 4096 + p) * 128 + dbase] = v;
        } else {
          #pragma unroll
          for (int r = 0; r < 4; ++r)
            Vt[((size_t)b * 128 + dbase + r) * 4096 + p] = (h16)acc[r];
        }
      }
    }
  }
}

// ---------------- K2: flash attention — 4 waves x 32 q, KVBLK=64, static dbuf ----------------
// grid 512: b = bid>>7, qb = (bid>>2)&31 (128 q/block), sp = bid&3. 2 blocks/CU.
__global__ __launch_bounds__(256, 2)
void k_attn(const h16* __restrict__ Q, const h16* __restrict__ K,
            const h16* __restrict__ Vt, h16* __restrict__ Opart,
            float* __restrict__ Mb, float* __restrict__ Lb){
  __shared__ __align__(16) char Kl[2][16384];   // [64 key][128 d] f16 swz, static dbuf
  __shared__ __align__(16) char Vl[2][16384];   // [128 d][64 key] f16 swz, static dbuf
  __shared__ __align__(16) char Pl[4][4096];    // per-wave [32 q][64 k] f16 swz

  int bid = blockIdx.x;
  int b = bid >> 7, qb = (bid >> 2) & 31, sp = bid & 3;
  int tid = threadIdx.x;
  int w = tid >> 6, lane = tid & 63, g4 = lane >> 4, ln = lane & 15;
  int q0 = qb * 128 + w * 32;

  half8 qf[2][4];
  #pragma unroll
  for (int qt = 0; qt < 2; ++qt)
    #pragma unroll
    for (int ks = 0; ks < 4; ++ks)
      qf[qt][ks] = *(const half8*)&Q[((size_t)b * 4096 + q0 + qt * 16 + ln) * 128 + ks * 32 + g4 * 8];

  f32x4 acc[2][8];
  #pragma unroll
  for (int qt = 0; qt < 2; ++qt)
    #pragma unroll
    for (int dt = 0; dt < 8; ++dt)
      acc[qt][dt] = fzero();
  float mrow[2] = {-1e30f, -1e30f};             // log2-domain (Q pre-scaled)
  float lrow[2] = {0.f, 0.f};

  int base0 = sp * 1024;

  auto stage = [&](char* kd, char* vd, int kv0){
    #pragma unroll
    for (int i = 0; i < 4; ++i){
      int off = i * 4096 + w * 1024 + lane * 16;
      int row = off >> 8, c16 = (off >> 4) & 15;
      gl_lds16(&K[((size_t)b * 4096 + kv0 + row) * 128 + ((c16 ^ (row & 7)) << 3)],
               kd + i * 4096 + w * 1024);
    }
    #pragma unroll
    for (int i = 0; i < 4; ++i){
      int off = i * 4096 + w * 1024 + lane * 16;
      int row = off >> 7, c16 = (off >> 4) & 7;
      gl_lds16(&Vt[((size_t)b * 128 + row) * 4096 + kv0 + ((c16 ^ (row & 7)) << 3)],
               vd + i * 4096 + w * 1024);
    }
  };

  stage(&Kl[0][0], &Vl[0][0], base0);
  __syncthreads();

  for (int t2 = 0; t2 < 8; ++t2){
    #pragma unroll
    for (int h = 0; h < 2; ++h){              // compile-time buffer index
      int t = t2 * 2 + h;
      int kv0 = base0 + t * 64;
      if ((h == 0) | (t2 < 7))
        stage(&Kl[1 - h][0], &Vl[1 - h][0], kv0 + 64);   // prefetch into other buffer

      // S^T = mfma(K, Q) — log2-scaled scores
      f32x4 s[4][2];
      #pragma unroll
      for (int kt = 0; kt < 4; ++kt)
        #pragma unroll
        for (int qt = 0; qt < 2; ++qt) s[kt][qt] = fzero();
      #pragma unroll
      for (int kt = 0; kt < 4; ++kt){
        int key = kt * 16 + ln;
        #pragma unroll
        for (int ks = 0; ks < 4; ++ks){
          half8 kf = *(const half8*)&Kl[h][key * 256 + (((ks * 4 + g4) ^ (key & 7)) << 4)];
          #pragma unroll
          for (int qt = 0; qt < 2; ++qt)
            s[kt][qt] = mfma16(kf, qf[qt][ks], s[kt][qt]);
        }
      }

      // online softmax (log2 domain) with defer-rescale THR=11.5
      #pragma unroll
      for (int qt = 0; qt < 2; ++qt){
        float mx = -1e30f;
        #pragma unroll
        for (int kt = 0; kt < 4; ++kt)
          #pragma unroll
          for (int r = 0; r < 4; ++r) mx = fmaxf(mx, s[kt][qt][r]);
        mx = fmaxf(mx, __shfl_xor(mx, 16));
        mx = fmaxf(mx, __shfl_xor(mx, 32));
        if (!__all(mx <= mrow[qt] + 11.5f)){
          float mnew = fmaxf(mrow[qt], mx);
          float scale = exp2f(mrow[qt] - mnew);
          lrow[qt] *= scale;
          #pragma unroll
          for (int r = 0; r < 4; ++r){
            float sc = __shfl(scale, g4 * 4 + r);
            #pragma unroll
            for (int dt = 0; dt < 8; ++dt) acc[qt][dt][r] *= sc;
          }
          mrow[qt] = mnew;
        }
        float ps = 0.f;
        int q = qt * 16 + ln;
        #pragma unroll
        for (int kt = 0; kt < 4; ++kt){
          float e0 = exp2f(s[kt][qt][0] - mrow[qt]);
          float e1 = exp2f(s[kt][qt][1] - mrow[qt]);
          float e2 = exp2f(s[kt][qt][2] - mrow[qt]);
          float e3 = exp2f(s[kt][qt][3] - mrow[qt]);
          ps += (e0 + e1) + (e2 + e3);
          u64 v = (u64)pkrtz(e0, e1) | ((u64)pkrtz(e2, e3) << 32);
          *(u64*)&Pl[w][q * 128 + ((kt * 32 + g4 * 8) ^ ((q & 7) << 4))] = v;
        }
        ps += __shfl_xor(ps, 16);
        ps += __shfl_xor(ps, 32);
        lrow[qt] += ps;
      }

      // PV
      #pragma unroll
      for (int st = 0; st < 2; ++st){
        half8 pa[2];
        #pragma unroll
        for (int qt = 0; qt < 2; ++qt){
          int q = qt * 16 + ln;
          pa[qt] = *(const half8*)&Pl[w][q * 128 + (((st * 4 + g4) ^ (q & 7)) << 4)];
        }
        #pragma unroll
        for (int dt = 0; dt < 8; ++dt){
          int row = dt * 16 + ln;
          half8 vf = *(const half8*)&Vl[h][row * 128 + (((st * 4 + g4) ^ (row & 7)) << 4)];
          #pragma unroll
          for (int qt = 0; qt < 2; ++qt)
            acc[qt][dt] = mfma16(pa[qt], vf, acc[qt][dt]);
        }
      }

      __syncthreads();   // drains prefetch (vmcnt0) + guards buffer swap
    }
  }

  // normalized partials (f16-safe under defer-max) + m,l (m log2-domain)
  int pb = (b * 64 + qb * 2 + (w >> 1)) * 4 + sp;
  #pragma unroll
  for (int qt = 0; qt < 2; ++qt){
    float inv = 1.f / lrow[qt];
    #pragma unroll
    for (int r = 0; r < 4; ++r){
      float invr = __shfl(inv, g4 * 4 + r);
      int qloc = (w & 1) * 32 + qt * 16 + g4 * 4 + r;
      #pragma unroll
      for (int dt = 0; dt < 8; ++dt)
        Opart[(size_t)pb * 8192 + qloc * 128 + dt * 16 + ln] = (h16)(acc[qt][dt][r] * invr);
    }
  }
  if (lane < 16){
    #pragma unroll
    for (int qt = 0; qt < 2; ++qt){
      int qloc = (w & 1) * 32 + qt * 16 + lane;
      Mb[pb * 64 + qloc] = mrow[qt];
      Lb[pb * 64 + qloc] = lrow[qt];
    }
  }
}

// ---------------- K3: out = x + lambda * Wv @ combine(Opart)  (fused, h16 Wv) ----------------
__global__ __launch_bounds__(256, 2)
void k_oproj(const float* __restrict__ x, const h16* __restrict__ Wvb,
             const h16* __restrict__ Opart, const float* __restrict__ Mb,
             const float* __restrict__ Lb, const float* __restrict__ lamp,
             float* __restrict__ y){
  int bid = blockIdx.x;
  int b = bid >> 6, g64 = bid & 63;             // 64-q granule == 64-p tile
  int p0 = g64 * 64;
  int tid = threadIdx.x;
  int w = tid >> 6, lane = tid & 63, g4 = lane >> 4, ln = lane & 15;
  float lam = lamp[0];
  int base = (b * 64 + g64) * 4;

  half8 of[4][4];
  #pragma unroll
  for (int pt = 0; pt < 4; ++pt){
    int p = pt * 16 + ln;
    float m0 = Mb[(base + 0) * 64 + p], m1 = Mb[(base + 1) * 64 + p];
    float m2 = Mb[(base + 2) * 64 + p], m3 = Mb[(base + 3) * 64 + p];
    float mmax = fmaxf(fmaxf(m0, m1), fmaxf(m2, m3));
    float w0 = exp2f(m0 - mmax) * Lb[(base + 0) * 64 + p];   // m log2-domain
    float w1 = exp2f(m1 - mmax) * Lb[(base + 1) * 64 + p];
    float w2 = exp2f(m2 - mmax) * Lb[(base + 2) * 64 + p];
    float w3 = exp2f(m3 - mmax) * Lb[(base + 3) * 64 + p];
    float inv = 1.f / (w0 + w1 + w2 + w3);
    w0 *= inv; w1 *= inv; w2 *= inv; w3 *= inv;
    #pragma unroll
    for (int ks = 0; ks < 4; ++ks){
      size_t eo = (size_t)p * 128 + ks * 32 + g4 * 8;
      half8 a0 = *(const half8*)&Opart[(size_t)(base + 0) * 8192 + eo];
      half8 a1 = *(const half8*)&Opart[(size_t)(base + 1) * 8192 + eo];
      half8 a2 = *(const half8*)&Opart[(size_t)(base + 2) * 8192 + eo];
      half8 a3 = *(const half8*)&Opart[(size_t)(base + 3) * 8192 + eo];
      half8 o;
      #pragma unroll
      for (int j = 0; j < 8; ++j)
        o[j] = (h16)(w0 * (float)a0[j] + w1 * (float)a1[j]
                   + w2 * (float)a2[j] + w3 * (float)a3[j]);
      of[pt][ks] = o;
    }
  }

  #pragma unroll
  for (int ctl = 0; ctl < 4; ++ctl){
    int crow = w * 64 + ctl * 16 + ln;
    half8 wf[4];
    #pragma unroll
    for (int ks = 0; ks < 4; ++ks)
      wf[ks] = *(const half8*)&Wvb[(size_t)crow * 128 + ks * 32 + g4 * 8];
    #pragma unroll
    for (int pt = 0; pt < 4; ++pt){
      f32x4 a = fzero();
      #pragma unroll
      for (int ks = 0; ks < 4; ++ks) a = mfma16(wf[ks], of[pt][ks], a);
      int p = p0 + pt * 16 + ln;
      int c = w * 64 + ctl * 16 + g4 * 4;
      #pragma unroll
      for (int r = 0; r < 4; ++r){
        size_t idx = ((size_t)b * 256 + c + r) * 4096 + p;
        y[idx] = x[idx] + lam * a[r];
      }
    }
  }
}

extern "C" void kernel_launch(void* const* d_in, const int* in_sizes, int n_in,
                              void* d_out, int out_size, void* d_ws, size_t ws_size,
                              hipStream_t stream) {
  const float* x   = (const float*)d_in[0];
  const float* Wg  = (const float*)d_in[1];
  const float* Wf  = (const float*)d_in[2];
  const float* Wh  = (const float*)d_in[3];
  const float* Wv  = (const float*)d_in[4];
  const float* lam = (const float*)d_in[5];

  h16* Wall  = (h16*)d_ws;                 // 131072 h16 (Wg,Wf,Wh,Wv f16)
  h16* Qb    = Wall + 131072;              // [4][4096][128] (pre-scaled by log2e)
  h16* Kb    = Qb + 2097152;               // [4][4096][128]
  h16* Vtb   = Kb + 2097152;               // [4][128][4096]
  h16* Opart = Vtb + 2097152;              // [1024][64][128] (normalized)
  float* Mb  = (float*)(Opart + 8388608);  // [1024][64] (log2-domain)
  float* Lb  = Mb + 65536;                 // [1024][64]

  k_cvtw<<<128, 256, 0, stream>>>(Wg, Wf, Wh, Wv, Wall);
  k_proj<<<256, 256, 0, stream>>>(x, Wall /*Wg*/, Wall + 65536 /*Wh*/, Wall + 32768 /*Wf*/,
                                  Qb, Kb, Vtb);
  k_attn<<<512, 256, 0, stream>>>(Qb, Kb, Vtb, Opart, Mb, Lb);
  k_oproj<<<256, 256, 0, stream>>>(x, Wall + 98304 /*Wv*/, Opart, Mb, Lb, lam, (float*)d_out);
}